// Round 1
// baseline (5383.584 us; speedup 1.0000x reference)
//
#include <hip/hip_runtime.h>

#define NN 100000
#define NE 3200000
#define FN 7
#define FE 6
#define FG 64
#define HID 32

__device__ __forceinline__ float leaky(float v) { return v >= 0.f ? v : 0.01f * v; }

__global__ __launch_bounds__(256) void edge_kernel(
    const float* __restrict__ x, const int* __restrict__ ei,
    const float* __restrict__ ea,
    const float* __restrict__ W1, const float* __restrict__ b1,
    const float* __restrict__ W2, const float* __restrict__ b2,
    float* __restrict__ summed, float* __restrict__ counts)
{
    int e = blockIdx.x * 256 + threadIdx.x;
    if (e >= NE) return;
    int row = ei[e];
    int col = ei[NE + e];

    float in[FN + FE];
    #pragma unroll
    for (int k = 0; k < FN; ++k) in[k] = x[row * FN + k];
    #pragma unroll
    for (int k = 0; k < FE; ++k) in[FN + k] = ea[e * FE + k];

    float h1[HID];
    #pragma unroll
    for (int j = 0; j < HID; ++j) {
        float acc = b1[j];
        #pragma unroll
        for (int k = 0; k < FN + FE; ++k) acc = fmaf(in[k], W1[k * HID + j], acc);
        h1[j] = leaky(acc);
    }

    float* base = summed + (size_t)col * HID;
    #pragma unroll
    for (int j = 0; j < HID; ++j) {
        float acc = b2[j];
        #pragma unroll
        for (int k = 0; k < HID; ++k) acc = fmaf(h1[k], W2[k * HID + j], acc);
        atomicAdd(base + j, acc);
    }
    atomicAdd(&counts[col], 1.0f);
}

__global__ __launch_bounds__(256) void node_kernel(
    const float* __restrict__ x, const float* __restrict__ summed,
    const float* __restrict__ counts, const float* __restrict__ u,
    const int* __restrict__ batch,
    const float* __restrict__ W3, const float* __restrict__ b3,
    const float* __restrict__ W4, const float* __restrict__ b4,
    float* __restrict__ out)
{
    int i = blockIdx.x * 256 + threadIdx.x;
    if (i >= NN) return;

    float h[FN + HID + FG];
    #pragma unroll
    for (int k = 0; k < FN; ++k) h[k] = x[i * FN + k];

    float inv = 1.f / fmaxf(counts[i], 1.f);
    #pragma unroll
    for (int k = 0; k < HID; ++k) h[FN + k] = summed[(size_t)i * HID + k] * inv;

    int b = batch[i];
    #pragma unroll
    for (int k = 0; k < FG; ++k) h[FN + HID + k] = u[b * FG + k];

    float g[HID];
    #pragma unroll
    for (int j = 0; j < HID; ++j) {
        float acc = b3[j];
        #pragma unroll
        for (int k = 0; k < FN + HID + FG; ++k) acc = fmaf(h[k], W3[k * HID + j], acc);
        g[j] = leaky(acc);
    }

    #pragma unroll
    for (int j = 0; j < FN; ++j) {
        float acc = b4[j];
        #pragma unroll
        for (int k = 0; k < HID; ++k) acc = fmaf(g[k], W4[k * FN + j], acc);
        out[i * FN + j] = acc;
    }
}

extern "C" void kernel_launch(void* const* d_in, const int* in_sizes, int n_in,
                              void* d_out, int out_size, void* d_ws, size_t ws_size,
                              hipStream_t stream)
{
    const float* x   = (const float*)d_in[0];
    const int*   ei  = (const int*)  d_in[1];
    const float* ea  = (const float*)d_in[2];
    const float* u   = (const float*)d_in[3];
    const int*   bat = (const int*)  d_in[4];
    const float* W1  = (const float*)d_in[5];
    const float* b1  = (const float*)d_in[6];
    const float* W2  = (const float*)d_in[7];
    const float* b2  = (const float*)d_in[8];
    const float* W3  = (const float*)d_in[9];
    const float* b3  = (const float*)d_in[10];
    const float* W4  = (const float*)d_in[11];
    const float* b4  = (const float*)d_in[12];
    float* out = (float*)d_out;

    float* summed = (float*)d_ws;                    // [NN, 32]
    float* counts = summed + (size_t)NN * HID;       // [NN]

    hipMemsetAsync(d_ws, 0, (size_t)NN * (HID + 1) * sizeof(float), stream);

    edge_kernel<<<(NE + 255) / 256, 256, 0, stream>>>(x, ei, ea, W1, b1, W2, b2,
                                                      summed, counts);
    node_kernel<<<(NN + 255) / 256, 256, 0, stream>>>(x, summed, counts, u, bat,
                                                      W3, b3, W4, b4, out);
}

// Round 2
// 1121.633 us; speedup vs baseline: 4.7998x; 4.7998x over previous
//
#include <hip/hip_runtime.h>

#define NN 100000
#define NE 3200000
#define FN 7
#define FE 6
#define FG 64
#define HID 32
#define NB ((NN + 1023) / 1024)   // 98 scan blocks

__device__ __forceinline__ float leaky(float v) { return v >= 0.f ? v : 0.01f * v; }

// ---- CSR build ----------------------------------------------------------

__global__ __launch_bounds__(256) void hist_kernel(const int* __restrict__ ei,
                                                   int* __restrict__ cnt)
{
    int e = blockIdx.x * 256 + threadIdx.x;
    if (e >= NE) return;
    atomicAdd(&cnt[ei[NE + e]], 1);
}

// per-1024-chunk exclusive scan; chunk totals to bsum
__global__ __launch_bounds__(1024) void scanA_kernel(const int* __restrict__ cnt,
                                                     int* __restrict__ off,
                                                     int* __restrict__ bsum)
{
    __shared__ int s[1024];
    int t = threadIdx.x;
    int i = blockIdx.x * 1024 + t;
    int v = (i < NN) ? cnt[i] : 0;
    s[t] = v;
    __syncthreads();
    for (int d = 1; d < 1024; d <<= 1) {
        int a = (t >= d) ? s[t - d] : 0;
        __syncthreads();
        s[t] += a;
        __syncthreads();
    }
    if (i < NN) off[i] = s[t] - v;          // exclusive within chunk
    if (t == 1023) bsum[blockIdx.x] = s[1023];
}

__global__ void scanB_kernel(int* __restrict__ bsum, int* __restrict__ boff)
{
    if (threadIdx.x == 0 && blockIdx.x == 0) {
        int run = 0;
        for (int b = 0; b < NB; ++b) { boff[b] = run; run += bsum[b]; }
    }
}

__global__ __launch_bounds__(256) void scanC_kernel(int* __restrict__ off,
                                                    const int* __restrict__ boff,
                                                    int* __restrict__ next)
{
    int i = blockIdx.x * 256 + threadIdx.x;
    if (i >= NN) return;
    int o = off[i] + boff[i >> 10];
    off[i] = o;
    next[i] = o;
}

__global__ __launch_bounds__(256) void perm_kernel(const int* __restrict__ ei,
                                                   int* __restrict__ next,
                                                   int* __restrict__ perm)
{
    int e = blockIdx.x * 256 + threadIdx.x;
    if (e >= NE) return;
    int pos = atomicAdd(&next[ei[NE + e]], 1);
    perm[pos] = e;
}

// ---- gather + edge-MLP recompute (4 lanes per node) ---------------------

__global__ __launch_bounds__(256) void agg_kernel(
    const float* __restrict__ x, const int* __restrict__ ei,
    const float* __restrict__ ea,
    const float* __restrict__ W1, const float* __restrict__ b1,
    const float* __restrict__ W2, const float* __restrict__ b2,
    const int* __restrict__ off, const int* __restrict__ cnt,
    const int* __restrict__ perm,
    float* __restrict__ summed)
{
    int gid = blockIdx.x * 256 + threadIdx.x;
    int node = gid >> 2;
    int part = gid & 3;
    if (node >= NN) return;

    int start = off[node];
    int deg   = cnt[node];

    float acc[HID];
    #pragma unroll
    for (int j = 0; j < HID; ++j) acc[j] = 0.f;
    int m = 0;

    for (int t = start + part; t < start + deg; t += 4) {
        int e   = perm[t];
        int row = ei[e];

        float in[FN + FE];
        #pragma unroll
        for (int k = 0; k < FN; ++k) in[k] = x[row * FN + k];
        #pragma unroll
        for (int k = 0; k < FE; ++k) in[FN + k] = ea[e * FE + k];

        float h[HID];
        #pragma unroll
        for (int j = 0; j < HID; ++j) {
            float a = b1[j];
            #pragma unroll
            for (int k = 0; k < FN + FE; ++k) a = fmaf(in[k], W1[k * HID + j], a);
            h[j] = leaky(a);
        }
        #pragma unroll
        for (int j = 0; j < HID; ++j) {
            float a = acc[j];
            #pragma unroll
            for (int k = 0; k < HID; ++k) a = fmaf(h[k], W2[k * HID + j], a);
            acc[j] = a;
        }
        ++m;
    }

    float fm = (float)m;
    #pragma unroll
    for (int j = 0; j < HID; ++j) {
        float a = fmaf(fm, b2[j], acc[j]);
        a += __shfl_xor(a, 1);
        a += __shfl_xor(a, 2);
        acc[j] = a;
    }
    if (part == 0) {
        #pragma unroll
        for (int j = 0; j < HID; ++j) summed[(size_t)node * HID + j] = acc[j];
    }
}

// ---- node MLP -----------------------------------------------------------

__global__ __launch_bounds__(256) void node_kernel(
    const float* __restrict__ x, const float* __restrict__ summed,
    const int* __restrict__ cnt, const float* __restrict__ u,
    const int* __restrict__ batch,
    const float* __restrict__ W3, const float* __restrict__ b3,
    const float* __restrict__ W4, const float* __restrict__ b4,
    float* __restrict__ out)
{
    int i = blockIdx.x * 256 + threadIdx.x;
    if (i >= NN) return;

    float h[FN + HID + FG];
    #pragma unroll
    for (int k = 0; k < FN; ++k) h[k] = x[i * FN + k];

    float inv = 1.f / fmaxf((float)cnt[i], 1.f);
    #pragma unroll
    for (int k = 0; k < HID; ++k) h[FN + k] = summed[(size_t)i * HID + k] * inv;

    int b = batch[i];
    #pragma unroll
    for (int k = 0; k < FG; ++k) h[FN + HID + k] = u[b * FG + k];

    float g[HID];
    #pragma unroll
    for (int j = 0; j < HID; ++j) {
        float acc = b3[j];
        #pragma unroll
        for (int k = 0; k < FN + HID + FG; ++k) acc = fmaf(h[k], W3[k * HID + j], acc);
        g[j] = leaky(acc);
    }

    #pragma unroll
    for (int j = 0; j < FN; ++j) {
        float acc = b4[j];
        #pragma unroll
        for (int k = 0; k < HID; ++k) acc = fmaf(g[k], W4[k * FN + j], acc);
        out[i * FN + j] = acc;
    }
}

// ---- launch -------------------------------------------------------------

extern "C" void kernel_launch(void* const* d_in, const int* in_sizes, int n_in,
                              void* d_out, int out_size, void* d_ws, size_t ws_size,
                              hipStream_t stream)
{
    const float* x   = (const float*)d_in[0];
    const int*   ei  = (const int*)  d_in[1];
    const float* ea  = (const float*)d_in[2];
    const float* u   = (const float*)d_in[3];
    const int*   bat = (const int*)  d_in[4];
    const float* W1  = (const float*)d_in[5];
    const float* b1  = (const float*)d_in[6];
    const float* W2  = (const float*)d_in[7];
    const float* b2  = (const float*)d_in[8];
    const float* W3  = (const float*)d_in[9];
    const float* b3  = (const float*)d_in[10];
    const float* W4  = (const float*)d_in[11];
    const float* b4  = (const float*)d_in[12];
    float* out = (float*)d_out;

    // workspace layout
    int*   cnt    = (int*)d_ws;            // [NN]
    int*   off    = cnt + NN;              // [NN]
    int*   next   = off + NN;              // [NN]
    int*   bsum   = next + NN;             // [NB]
    int*   boff   = bsum + NB;             // [NB]
    int*   perm   = boff + NB;             // [NE]
    float* summed = (float*)(perm + NE);   // [NN*HID]

    hipMemsetAsync(cnt, 0, (size_t)NN * sizeof(int), stream);

    hist_kernel<<<(NE + 255) / 256, 256, 0, stream>>>(ei, cnt);
    scanA_kernel<<<NB, 1024, 0, stream>>>(cnt, off, bsum);
    scanB_kernel<<<1, 64, 0, stream>>>(bsum, boff);
    scanC_kernel<<<(NN + 255) / 256, 256, 0, stream>>>(off, boff, next);
    perm_kernel<<<(NE + 255) / 256, 256, 0, stream>>>(ei, next, perm);

    agg_kernel<<<(NN * 4 + 255) / 256, 256, 0, stream>>>(
        x, ei, ea, W1, b1, W2, b2, off, cnt, perm, summed);

    node_kernel<<<(NN + 255) / 256, 256, 0, stream>>>(
        x, summed, cnt, u, bat, W3, b3, W4, b4, out);
}